// Round 12
// baseline (630.742 us; speedup 1.0000x reference)
//
#include <hip/hip_runtime.h>
#include <math.h>

#define NDIM 128   // in_dim = hid = out_dim
#define H2   256   // 2*hid
#define MAXG 2
#define TPE  8192  // edges per bin tile
#define NBKMAX 512 // max buckets (N <= 65536, 128 nodes/bucket)
#define WXB  192   // wprep blocks appended per y-slice of binA

typedef __attribute__((ext_vector_type(8))) short bf16x8;
typedef __attribute__((ext_vector_type(4))) float f32x4;

__device__ __forceinline__ unsigned short f2bf(float f) {
    unsigned int u = __float_as_uint(f);
    u += 0x7fffu + ((u >> 16) & 1u);           // RNE
    return (unsigned short)(u >> 16);
}
__device__ __forceinline__ float bf2f(unsigned short h) {
    return __uint_as_float(((unsigned int)h) << 16);
}
__device__ __forceinline__ void split2(float f, unsigned short& h, unsigned short& l) {
    h = f2bf(f);
    l = f2bf(f - bf2f(h));
}

// ================= binned edge build (no global atomics) =================
struct BinArgs {
    const int* src[MAXG]; const int* dst[MAXG];
    int* histD[MAXG]; int* histS[MAXG];     // [NT][NBK] counts -> global run offsets
    int* totD[MAXG];  int* baseD[MAXG];
    int* totS[MAXG];  int* baseS[MAXG];
    unsigned int* pairs[MAXG];              // dst-binned packed (dl<<16|src)
    unsigned short* srcS[MAXG];             // src-binned bare src ids
    int E[MAXG]; int NBK; int NT; int n;
};

// weight-prep args (merged into binA as extra blocks)
struct WPArgs {
    const float* src[4];
    unsigned short* Hd[4]; unsigned short* Ld[4];
};

__global__ __launch_bounds__(256) void binA(BinArgs a, WPArgs w) {
    int t = blockIdx.x, tid = threadIdx.x;
    if (t >= a.NT) {
        // ---- wprep path: transpose + split all 4 weights ----
        int i = (blockIdx.y * WXB + (t - a.NT)) * 256 + tid;
        const float* Wsrc; unsigned short *Hd, *Ld; int K, Nc, idx;
        if (i < 32768)       { Wsrc = w.src[0]; Hd = w.Hd[0]; Ld = w.Ld[0]; K = 128; Nc = 256; idx = i; }
        else if (i < 65536)  { Wsrc = w.src[1]; Hd = w.Hd[1]; Ld = w.Ld[1]; K = 256; Nc = 128; idx = i - 32768; }
        else if (i < 81920)  { Wsrc = w.src[2]; Hd = w.Hd[2]; Ld = w.Ld[2]; K = 128; Nc = 128; idx = i - 65536; }
        else                 { Wsrc = w.src[3]; Hd = w.Hd[3]; Ld = w.Ld[3]; K = 128; Nc = 128; idx = i - 81920; }
        int k = idx / Nc, n = idx % Nc;
        unsigned short h, l;
        split2(Wsrc[idx], h, l);
        Hd[n * K + k] = h;
        Ld[n * K + k] = l;
        return;
    }
    __shared__ int cntD[NBKMAX], cntS[NBKMAX];
    int g = blockIdx.y;
    for (int b = tid; b < NBKMAX; b += 256) { cntD[b] = 0; cntS[b] = 0; }
    __syncthreads();
    int E = a.E[g];
    int base = t * TPE;
#pragma unroll
    for (int k = 0; k < TPE / 256; ++k) {
        int e = base + k * 256 + tid;
        if (e < E) {
            atomicAdd(&cntD[a.dst[g][e] >> 7], 1);
            atomicAdd(&cntS[a.src[g][e] >> 7], 1);
        }
    }
    __syncthreads();
    for (int b = tid; b < a.NBK; b += 256) {
        a.histD[g][t * a.NBK + b] = cntD[b];
        a.histS[g][t * a.NBK + b] = cntS[b];
    }
}

// fused: per-bucket totals + exclusive scan + rewrite hist to global run offsets
__global__ __launch_bounds__(512) void binB(BinArgs a) {
    int g = blockIdx.y, side = blockIdx.z;
    int* hist = side ? a.histS[g] : a.histD[g];
    int* tot  = side ? a.totS[g]  : a.totD[g];
    int* base = side ? a.baseS[g] : a.baseD[g];
    __shared__ int s[512];
    int b = threadIdx.x;
    int v = 0;
    if (b < a.NBK)
        for (int t = 0; t < a.NT; ++t) v += hist[t * a.NBK + b];
    s[b] = v;
    __syncthreads();
    for (int off = 1; off < 512; off <<= 1) {
        int u = (b >= off) ? s[b - off] : 0;
        __syncthreads();
        s[b] += u;
        __syncthreads();
    }
    int excl = s[b] - v;
    if (b < a.NBK) {
        tot[b] = v;
        base[b] = excl;
        int run = excl;
        for (int t = 0; t < a.NT; ++t) {
            int h = hist[t * a.NBK + b];
            hist[t * a.NBK + b] = run;
            run += h;
        }
    }
}

__global__ __launch_bounds__(256) void binC(BinArgs a) {
    __shared__ int offD[NBKMAX], offS[NBKMAX];
    int g = blockIdx.y, t = blockIdx.x, tid = threadIdx.x;
    for (int b = tid; b < a.NBK; b += 256) {
        offD[b] = a.histD[g][t * a.NBK + b];
        offS[b] = a.histS[g][t * a.NBK + b];
    }
    __syncthreads();
    int E = a.E[g];
    int base = t * TPE;
    unsigned int* pairs = a.pairs[g];
    unsigned short* ss = a.srcS[g];
#pragma unroll
    for (int k = 0; k < TPE / 256; ++k) {
        int e = base + k * 256 + tid;
        if (e < E) {
            int s = a.src[g][e], d = a.dst[g][e];
            int pos = atomicAdd(&offD[d >> 7], 1);
            pairs[pos] = ((unsigned int)(d & 127) << 16) | (unsigned int)s;
            int posS = atomicAdd(&offS[s >> 7], 1);
            ss[posS] = (unsigned short)s;
        }
    }
}

// fused: out-degree hist (-> ns) + per-bucket counting sort (-> CSR, nd, u16 edges)
struct FinArgs {
    const unsigned int* pairs[MAXG];
    const unsigned short* srcS[MAXG];
    const int* totD[MAXG]; const int* baseD[MAXG];
    const int* totS[MAXG]; const int* baseS[MAXG];
    int* row_ptr[MAXG]; int* row_end[MAXG];
    unsigned short* edge_srt[MAXG];
    float* ns[MAXG]; float* nd[MAXG];
    int n;
};

__global__ __launch_bounds__(256) void finalize(FinArgs a) {
    __shared__ int cnt[128], hist[128], scn[128], cur[128];
    int g = blockIdx.y, bkt = blockIdx.x, tid = threadIdx.x;
    if (tid < 128) { cnt[tid] = 0; hist[tid] = 0; }
    __syncthreads();
    // --- out-degree from src-binned segment -> ns ---
    {
        int base = a.baseS[g][bkt], tot = a.totS[g][bkt];
        const unsigned short* ss = a.srcS[g];
        for (int i = tid; i < tot; i += 256)
            atomicAdd(&cnt[ss[base + i] & 127], 1);
    }
    // --- in-degree hist of dst-binned pairs ---
    int cntE = a.totD[g][bkt], base = a.baseD[g][bkt];
    const unsigned int* pp = a.pairs[g] + base;
    for (int i = tid; i < cntE; i += 256)
        atomicAdd(&hist[pp[i] >> 16], 1);
    __syncthreads();
    if (tid < 128) {
        int node = bkt * 128 + tid;
        if (node < a.n) {
            int c = cnt[tid];
            a.ns[g][node] = rsqrtf((float)(c > 1 ? c : 1));
        }
        scn[tid] = hist[tid];
    }
    __syncthreads();
    for (int off = 1; off < 128; off <<= 1) {
        int v = (tid < 128 && tid >= off) ? scn[tid - off] : 0;
        __syncthreads();
        if (tid < 128) scn[tid] += v;
        __syncthreads();
    }
    if (tid < 128) {
        int incl = scn[tid];
        int h = hist[tid];
        cur[tid] = incl - h;
        int node = bkt * 128 + tid;
        if (node < a.n) {
            a.row_ptr[g][node] = base + incl - h;
            a.row_end[g][node] = base + incl;
            a.nd[g][node] = rsqrtf((float)(h > 1 ? h : 1));
        }
    }
    __syncthreads();
    for (int i = tid; i < cntE; i += 256) {
        unsigned int p = pp[i];
        int pos = atomicAdd(&cur[p >> 16], 1);
        a.edge_srt[g][base + pos] = (unsigned short)(p & 0xFFFF);
    }
}

// ====== GATHER + FUSED double-GEMM, one kernel, 256 threads (4 waves) ======
// ROWS=16 (r11 post-mortem): the gather is outstanding-requests-limited, not
// wave-count or per-wave-ILP limited (allocator refuses deep pipelines). 256-thr
// blocks with 16KB/8KB LDS allow 8 blocks/CU = 64 half-wave gather chains/CU
// (~1.7x the resident chains of the 512-thr version) + finer gather/GEMM mixing
// + smaller barrier convoy (max over 8 chains, not 16).
// GMODE 1: acc += X[src]*sns[src]       (gather1 semantics)
// GMODE 2: acc += X[src]; relu(acc*nd + gbias)  (gather2 semantics)
struct FusedArgs {
    const float* Xg[MAXG];                         // gather source (fp32, NDIM cols)
    const int* rp[MAXG]; const int* re[MAXG];
    const unsigned short* ep[MAXG];
    const float* sns[MAXG];                        // GMODE1 per-src scale
    const float* ndv[MAXG];                        // GMODE2 per-row scale
    const float* gbias;                            // GMODE2 bias
    const unsigned short* B1h; const unsigned short* B1l;
    const unsigned short* B2h; const unsigned short* B2l;
    const float* rs1[MAXG]; const float* rs2[MAXG];
    const float* b1v; const float* b2v;
    float* C[MAXG];
    int M, has_rs1, has_rs2, has_b1, has_b2;
};

template <int K1, int N1, int ACT1, int ROWS, int GMODE>
__global__ __launch_bounds__(256, 8) void fused_g(FusedArgs a) {
    constexpr int IR   = ROWS / 16;                 // = 1
    constexpr int SH_A = ROWS * K1;                 // shorts per plane (linear)
    constexpr int SH_X = ROWS * N1;
    constexpr int SH   = (2 * SH_A > 2 * SH_X) ? 2 * SH_A : 2 * SH_X;
    __shared__ __align__(16) unsigned short S[SH];
    unsigned short* As_h = S;
    unsigned short* As_l = S + SH_A;
    unsigned short* Xs_h = S;                       // union: A dead before X written
    unsigned short* Xs_l = S + SH_X;

    int g = blockIdx.y;
    const unsigned short* __restrict__ B1h = a.B1h;
    const unsigned short* __restrict__ B1l = a.B1l;
    const unsigned short* __restrict__ B2h = a.B2h;
    const unsigned short* __restrict__ B2l = a.B2l;

    int tid  = threadIdx.x;
    int wave = tid >> 6, lane = tid & 63;
    int quad = lane >> 4, l16 = lane & 15;
    int rowBase = blockIdx.x * ROWS;
    int M = a.M;

    // ---- phase 0: gather ROWS rows -> As (split h/l, swizzled) ----
    {
        int half  = tid >> 5;                       // 0..7 half-wave id
        int glane = tid & 31;
        const float* X   = a.Xg[g];
        const float* sns = a.sns[g];
        const unsigned short* ep = a.ep[g];
        int base = glane * 4;
#pragma unroll
        for (int ps = 0; ps < ROWS / 8; ++ps) {
            int row  = ps * 8 + half;
            int grow = rowBase + row;
            float4 acc = make_float4(0.f, 0.f, 0.f, 0.f);
            if (grow < M) {
                int j = a.rp[g][grow], end = a.re[g][grow];
                if (GMODE == 1) {
                    // 8-edge groups: 8 loads issued, sched_barrier pins above fmas
                    for (; j + 7 < end; j += 8) {
                        int s0 = ep[j], s1 = ep[j + 1], s2 = ep[j + 2], s3 = ep[j + 3];
                        int s4 = ep[j + 4], s5 = ep[j + 5], s6 = ep[j + 6], s7 = ep[j + 7];
                        float n0 = sns[s0], n1 = sns[s1], n2 = sns[s2], n3 = sns[s3];
                        float n4 = sns[s4], n5 = sns[s5], n6 = sns[s6], n7 = sns[s7];
                        float4 v0 = *(const float4*)(X + (size_t)s0 * NDIM + base);
                        float4 v1 = *(const float4*)(X + (size_t)s1 * NDIM + base);
                        float4 v2 = *(const float4*)(X + (size_t)s2 * NDIM + base);
                        float4 v3 = *(const float4*)(X + (size_t)s3 * NDIM + base);
                        float4 v4 = *(const float4*)(X + (size_t)s4 * NDIM + base);
                        float4 v5 = *(const float4*)(X + (size_t)s5 * NDIM + base);
                        float4 v6 = *(const float4*)(X + (size_t)s6 * NDIM + base);
                        float4 v7 = *(const float4*)(X + (size_t)s7 * NDIM + base);
                        __builtin_amdgcn_sched_barrier(0);
                        acc.x = fmaf(v0.x, n0, fmaf(v1.x, n1, fmaf(v2.x, n2, fmaf(v3.x, n3, acc.x))));
                        acc.y = fmaf(v0.y, n0, fmaf(v1.y, n1, fmaf(v2.y, n2, fmaf(v3.y, n3, acc.y))));
                        acc.z = fmaf(v0.z, n0, fmaf(v1.z, n1, fmaf(v2.z, n2, fmaf(v3.z, n3, acc.z))));
                        acc.w = fmaf(v0.w, n0, fmaf(v1.w, n1, fmaf(v2.w, n2, fmaf(v3.w, n3, acc.w))));
                        acc.x = fmaf(v4.x, n4, fmaf(v5.x, n5, fmaf(v6.x, n6, fmaf(v7.x, n7, acc.x))));
                        acc.y = fmaf(v4.y, n4, fmaf(v5.y, n5, fmaf(v6.y, n6, fmaf(v7.y, n7, acc.y))));
                        acc.z = fmaf(v4.z, n4, fmaf(v5.z, n5, fmaf(v6.z, n6, fmaf(v7.z, n7, acc.z))));
                        acc.w = fmaf(v4.w, n4, fmaf(v5.w, n5, fmaf(v6.w, n6, fmaf(v7.w, n7, acc.w))));
                    }
                    for (; j + 3 < end; j += 4) {
                        int s0 = ep[j], s1 = ep[j + 1], s2 = ep[j + 2], s3 = ep[j + 3];
                        float n0 = sns[s0], n1 = sns[s1], n2 = sns[s2], n3 = sns[s3];
                        float4 v0 = *(const float4*)(X + (size_t)s0 * NDIM + base);
                        float4 v1 = *(const float4*)(X + (size_t)s1 * NDIM + base);
                        float4 v2 = *(const float4*)(X + (size_t)s2 * NDIM + base);
                        float4 v3 = *(const float4*)(X + (size_t)s3 * NDIM + base);
                        acc.x = fmaf(v0.x, n0, fmaf(v1.x, n1, fmaf(v2.x, n2, fmaf(v3.x, n3, acc.x))));
                        acc.y = fmaf(v0.y, n0, fmaf(v1.y, n1, fmaf(v2.y, n2, fmaf(v3.y, n3, acc.y))));
                        acc.z = fmaf(v0.z, n0, fmaf(v1.z, n1, fmaf(v2.z, n2, fmaf(v3.z, n3, acc.z))));
                        acc.w = fmaf(v0.w, n0, fmaf(v1.w, n1, fmaf(v2.w, n2, fmaf(v3.w, n3, acc.w))));
                    }
                    for (; j < end; ++j) {
                        int s0 = ep[j];
                        float n0 = sns[s0];
                        float4 v0 = *(const float4*)(X + (size_t)s0 * NDIM + base);
                        acc.x = fmaf(v0.x, n0, acc.x); acc.y = fmaf(v0.y, n0, acc.y);
                        acc.z = fmaf(v0.z, n0, acc.z); acc.w = fmaf(v0.w, n0, acc.w);
                    }
                } else {
                    for (; j + 7 < end; j += 8) {
                        int s0 = ep[j], s1 = ep[j + 1], s2 = ep[j + 2], s3 = ep[j + 3];
                        int s4 = ep[j + 4], s5 = ep[j + 5], s6 = ep[j + 6], s7 = ep[j + 7];
                        float4 v0 = *(const float4*)(X + (size_t)s0 * NDIM + base);
                        float4 v1 = *(const float4*)(X + (size_t)s1 * NDIM + base);
                        float4 v2 = *(const float4*)(X + (size_t)s2 * NDIM + base);
                        float4 v3 = *(const float4*)(X + (size_t)s3 * NDIM + base);
                        float4 v4 = *(const float4*)(X + (size_t)s4 * NDIM + base);
                        float4 v5 = *(const float4*)(X + (size_t)s5 * NDIM + base);
                        float4 v6 = *(const float4*)(X + (size_t)s6 * NDIM + base);
                        float4 v7 = *(const float4*)(X + (size_t)s7 * NDIM + base);
                        __builtin_amdgcn_sched_barrier(0);
                        acc.x += v0.x + v1.x + v2.x + v3.x;
                        acc.y += v0.y + v1.y + v2.y + v3.y;
                        acc.z += v0.z + v1.z + v2.z + v3.z;
                        acc.w += v0.w + v1.w + v2.w + v3.w;
                        acc.x += v4.x + v5.x + v6.x + v7.x;
                        acc.y += v4.y + v5.y + v6.y + v7.y;
                        acc.z += v4.z + v5.z + v6.z + v7.z;
                        acc.w += v4.w + v5.w + v6.w + v7.w;
                    }
                    for (; j + 3 < end; j += 4) {
                        int s0 = ep[j], s1 = ep[j + 1], s2 = ep[j + 2], s3 = ep[j + 3];
                        float4 v0 = *(const float4*)(X + (size_t)s0 * NDIM + base);
                        float4 v1 = *(const float4*)(X + (size_t)s1 * NDIM + base);
                        float4 v2 = *(const float4*)(X + (size_t)s2 * NDIM + base);
                        float4 v3 = *(const float4*)(X + (size_t)s3 * NDIM + base);
                        acc.x += v0.x + v1.x + v2.x + v3.x;
                        acc.y += v0.y + v1.y + v2.y + v3.y;
                        acc.z += v0.z + v1.z + v2.z + v3.z;
                        acc.w += v0.w + v1.w + v2.w + v3.w;
                    }
                    for (; j < end; ++j) {
                        int s0 = ep[j];
                        float4 v0 = *(const float4*)(X + (size_t)s0 * NDIM + base);
                        acc.x += v0.x; acc.y += v0.y; acc.z += v0.z; acc.w += v0.w;
                    }
                }
            }
            float v[4] = {acc.x, acc.y, acc.z, acc.w};
            if (GMODE == 2) {
                float s = (grow < M) ? a.ndv[g][grow] : 0.f;
#pragma unroll
                for (int c = 0; c < 4; ++c)
                    v[c] = fmaxf(v[c] * s + a.gbias[base + c], 0.f);
            }
            unsigned short h[4], l[4];
#pragma unroll
            for (int c = 0; c < 4; ++c) split2(v[c], h[c], l[c]);
            // swizzled LDS write: cols glane*4..+3 all in chunk oc=glane>>1
            int oc = glane >> 1, within = (glane & 1) * 4;
            int sc = oc ^ (row & 7);
            *(ushort4*)(As_h + row * K1 + sc * 8 + within) = make_ushort4(h[0], h[1], h[2], h[3]);
            *(ushort4*)(As_l + row * K1 + sc * 8 + within) = make_ushort4(l[0], l[1], l[2], l[3]);
        }
    }

    constexpr int J1  = N1 / 64;                   // pass1 16-col groups per wave (4 waves)
    constexpr int KT1 = K1 / 32;
    constexpr int KT2 = N1 / 32;
    int wcol1 = wave * (N1 / 4);
    int wcol2 = wave * 32;

    size_t b1off[J1];
#pragma unroll
    for (int j = 0; j < J1; ++j)
        b1off[j] = (size_t)(wcol1 + j * 16 + l16) * K1 + quad * 8;
    size_t b2off[2];
#pragma unroll
    for (int j = 0; j < 2; ++j)
        b2off[j] = (size_t)(wcol2 + j * 16 + l16) * N1 + quad * 8;

    auto loadB1 = [&](int kt, bf16x8 (&bh)[J1], bf16x8 (&bl)[J1]) {
#pragma unroll
        for (int j = 0; j < J1; ++j) {
            bh[j] = *(const bf16x8*)(B1h + b1off[j] + kt * 32);
            bl[j] = *(const bf16x8*)(B1l + b1off[j] + kt * 32);
        }
    };
    auto loadB2 = [&](int kt, bf16x8 (&bh)[2], bf16x8 (&bl)[2]) {
#pragma unroll
        for (int j = 0; j < 2; ++j) {
            bh[j] = *(const bf16x8*)(B2h + b2off[j] + kt * 32);
            bl[j] = *(const bf16x8*)(B2l + b2off[j] + kt * 32);
        }
    };

    // ---- preload B1(kt=0): latency hides under barrier ----
    bf16x8 b1hA[J1], b1lA[J1], b1hB[J1], b1lB[J1];
    loadB1(0, b1hA, b1lA);
    __syncthreads();

    // ---- pass 1: ROWS x N1, ping-pong B1 buffers ----
    f32x4 acc1[IR][J1] = {};
    auto stepP1 = [&](int kt, bf16x8 (&bh)[J1], bf16x8 (&bl)[J1]) {
        bf16x8 af[IR], alf[IR];
#pragma unroll
        for (int i = 0; i < IR; ++i) {
            int r  = i * 16 + l16;
            int sc = (kt * 4 + quad) ^ (r & 7);    // swizzled read
            af[i]  = *(const bf16x8*)(As_h + r * K1 + sc * 8);
            alf[i] = *(const bf16x8*)(As_l + r * K1 + sc * 8);
        }
#pragma unroll
        for (int i = 0; i < IR; ++i)
#pragma unroll
            for (int j = 0; j < J1; ++j) {
                acc1[i][j] = __builtin_amdgcn_mfma_f32_16x16x32_bf16(af[i],  bh[j], acc1[i][j], 0, 0, 0);
                acc1[i][j] = __builtin_amdgcn_mfma_f32_16x16x32_bf16(alf[i], bh[j], acc1[i][j], 0, 0, 0);
                acc1[i][j] = __builtin_amdgcn_mfma_f32_16x16x32_bf16(af[i],  bl[j], acc1[i][j], 0, 0, 0);
            }
    };
#pragma unroll
    for (int kt = 0; kt < KT1; kt += 2) {
        if (kt + 1 < KT1) loadB1(kt + 1, b1hB, b1lB);
        stepP1(kt, b1hA, b1lA);
        if (kt + 2 < KT1) loadB1(kt + 2, b1hA, b1lA);
        if (kt + 1 < KT1) stepP1(kt + 1, b1hB, b1lB);
    }

    // ---- preload B2(kt=0): latency hides under epilogue1 + barriers ----
    bf16x8 b2hA[2], b2lA[2], b2hB[2], b2lB[2];
    loadB2(0, b2hA, b2lA);

    __syncthreads();   // all waves done reading As before Xs overwrite

    // ---- epilogue 1: act -> split -> swizzled LDS hidden tile ----
    const float* rs1p = a.has_rs1 ? a.rs1[g] : nullptr;
#pragma unroll
    for (int i = 0; i < IR; ++i) {
#pragma unroll
        for (int rr = 0; rr < 4; ++rr) {
            int row  = i * 16 + quad * 4 + rr;
            int grow = rowBase + row;
            float rs = 1.0f;
            if (rs1p) rs = (grow < M) ? rs1p[grow] : 0.0f;
#pragma unroll
            for (int j = 0; j < J1; ++j) {
                int col = wcol1 + j * 16 + l16;
                float v = acc1[i][j][rr] * rs;
                if (a.has_b1) v += a.b1v[col];
                if (ACT1 == 1) v = fmaxf(v, 0.f);
                else           v = v > 0.f ? v : expm1f(v);
                unsigned short h, l;
                split2(v, h, l);
                int oc = col >> 3, within = col & 7;
                int sc = oc ^ (row & 7);
                Xs_h[row * N1 + sc * 8 + within] = h;
                Xs_l[row * N1 + sc * 8 + within] = l;
            }
        }
    }
    __syncthreads();

    // ---- pass 2: hidden(ROWS x N1) @ B2(N1 x 128), ping-pong B2 buffers ----
    f32x4 acc2[IR][2] = {};
    auto stepP2 = [&](int kt, bf16x8 (&bh)[2], bf16x8 (&bl)[2]) {
        bf16x8 xf[IR], xlf[IR];
#pragma unroll
        for (int i = 0; i < IR; ++i) {
            int r  = i * 16 + l16;
            int sc = (kt * 4 + quad) ^ (r & 7);
            xf[i]  = *(const bf16x8*)(Xs_h + r * N1 + sc * 8);
            xlf[i] = *(const bf16x8*)(Xs_l + r * N1 + sc * 8);
        }
#pragma unroll
        for (int i = 0; i < IR; ++i)
#pragma unroll
            for (int j = 0; j < 2; ++j) {
                acc2[i][j] = __builtin_amdgcn_mfma_f32_16x16x32_bf16(xf[i],  bh[j], acc2[i][j], 0, 0, 0);
                acc2[i][j] = __builtin_amdgcn_mfma_f32_16x16x32_bf16(xlf[i], bh[j], acc2[i][j], 0, 0, 0);
                acc2[i][j] = __builtin_amdgcn_mfma_f32_16x16x32_bf16(xf[i],  bl[j], acc2[i][j], 0, 0, 0);
            }
    };
#pragma unroll
    for (int kt = 0; kt < KT2; kt += 2) {
        if (kt + 1 < KT2) loadB2(kt + 1, b2hB, b2lB);
        stepP2(kt, b2hA, b2lA);
        if (kt + 2 < KT2) loadB2(kt + 2, b2hA, b2lA);
        if (kt + 1 < KT2) stepP2(kt + 1, b2hB, b2lB);
    }

    // ---- epilogue 2: fp32 out ----
    const float* rs2p = a.has_rs2 ? a.rs2[g] : nullptr;
#pragma unroll
    for (int i = 0; i < IR; ++i) {
#pragma unroll
        for (int rr = 0; rr < 4; ++rr) {
            int grow = rowBase + i * 16 + quad * 4 + rr;
            if (grow >= M) continue;
            float rs = rs2p ? rs2p[grow] : 1.0f;
#pragma unroll
            for (int j = 0; j < 2; ++j) {
                int col = wcol2 + j * 16 + l16;
                float v = acc2[i][j][rr] * rs;
                if (a.has_b2) v += a.b2v[col];
                a.C[g][(size_t)grow * NDIM + col] = v;
            }
        }
    }
}

extern "C" void kernel_launch(void* const* d_in, const int* in_sizes, int n_in,
                              void* d_out, int out_size, void* d_ws, size_t ws_size,
                              hipStream_t stream) {
    const float* feat[2] = {(const float*)d_in[0], (const float*)d_in[1]};
    const int*   ei[2]   = {(const int*)d_in[2], (const int*)d_in[3]};
    const float* W1   = (const float*)d_in[4];
    const float* b1   = (const float*)d_in[5];
    const float* W2   = (const float*)d_in[6];
    const float* b2   = (const float*)d_in[7];
    const float* fc1W = (const float*)d_in[8];
    const float* fc1b = (const float*)d_in[9];
    const float* fc2W = (const float*)d_in[10];
    const float* fc2b = (const float*)d_in[11];
    int N = in_sizes[0] / NDIM;     // 50000 (< 65536: u16 node-id packing valid)
    float* out = (float*)d_out;

    int Emax = 0;
    for (int g = 0; g < 2; ++g) { int E = in_sizes[2 + g] / 2; if (E > Emax) Emax = E; }
    int NBK = (N + 127) / 128;
    int NT  = (Emax + TPE - 1) / TPE;

    // ---- workspace layout ----
    char* p = (char*)d_ws;
    float* ns_[2]; float* nd_[2];
    for (int i = 0; i < 2; ++i) { ns_[i] = (float*)p; p += (size_t)N * 4; }
    for (int i = 0; i < 2; ++i) { nd_[i] = (float*)p; p += (size_t)N * 4; }
    int* rp_[2]; int* re_[2]; unsigned short* esrt_[2];
    for (int i = 0; i < 2; ++i) { rp_[i] = (int*)p; p += (size_t)N * 4; }
    for (int i = 0; i < 2; ++i) { re_[i] = (int*)p; p += (size_t)N * 4; }
    for (int i = 0; i < 2; ++i) { esrt_[i] = (unsigned short*)p; p += (size_t)Emax * 2; }
    unsigned short* R1[2]; unsigned short* R2[2];
    for (int i = 0; i < 2; ++i) { R1[i] = (unsigned short*)p; p += (size_t)N * NDIM * 2 * 2; }
    for (int i = 0; i < 2; ++i) { R2[i] = (unsigned short*)p; p += (size_t)N * H2 * 2 * 2; }
    unsigned short* W1th = (unsigned short*)p; p += (size_t)NDIM * H2 * 2;
    unsigned short* W1tl = (unsigned short*)p; p += (size_t)NDIM * H2 * 2;
    unsigned short* W2th = (unsigned short*)p; p += (size_t)H2 * NDIM * 2;
    unsigned short* W2tl = (unsigned short*)p; p += (size_t)H2 * NDIM * 2;
    unsigned short* f1th = (unsigned short*)p; p += (size_t)NDIM * NDIM * 2;
    unsigned short* f1tl = (unsigned short*)p; p += (size_t)NDIM * NDIM * 2;
    unsigned short* f2th = (unsigned short*)p; p += (size_t)NDIM * NDIM * 2;
    unsigned short* f2tl = (unsigned short*)p; p += (size_t)NDIM * NDIM * 2;
    int* tb = (int*)p; p += (size_t)2 * 4 * NBK * 4;   // totD/baseD/totS/baseS per graph

    // aliases with disjoint lifetimes:
    //  - histD/histS at R2[i]+0 (dead after binC); pairs at R2[i]+1MB (dead after finalize)
    //  - srcS at R1[i] (dead after finalize)
    //  - T (fp32, N*128) at R2[i][0 : N*256 shorts] (written by fused_g12 after
    //    pairs dead; read by fused_g34)
    int* histD_[2]; int* histS_[2]; unsigned int* pairs_[2]; unsigned short* srcS_[2];
    for (int i = 0; i < 2; ++i) {
        histD_[i] = (int*)R2[i];
        histS_[i] = (int*)R2[i] + (size_t)NT * NBK;
        pairs_[i] = (unsigned int*)((char*)R2[i] + (1 << 20));  // 1MB offset > hist tables
        srcS_[i]  = (unsigned short*)R1[i];
    }

    BinArgs ba = {};
    ba.NBK = NBK; ba.NT = NT; ba.n = N;
    for (int i = 0; i < 2; ++i) {
        int E = in_sizes[2 + i] / 2;
        ba.src[i] = ei[i]; ba.dst[i] = ei[i] + E; ba.E[i] = E;
        ba.histD[i] = histD_[i]; ba.histS[i] = histS_[i];
        ba.totD[i]  = tb + (size_t)i * 4 * NBK;
        ba.baseD[i] = tb + (size_t)i * 4 * NBK + NBK;
        ba.totS[i]  = tb + (size_t)i * 4 * NBK + 2 * NBK;
        ba.baseS[i] = tb + (size_t)i * 4 * NBK + 3 * NBK;
        ba.pairs[i] = pairs_[i]; ba.srcS[i] = srcS_[i];
    }

    WPArgs wp = {};
    wp.src[0] = W1;   wp.Hd[0] = W1th; wp.Ld[0] = W1tl;
    wp.src[1] = W2;   wp.Hd[1] = W2th; wp.Ld[1] = W2tl;
    wp.src[2] = fc1W; wp.Hd[2] = f1th; wp.Ld[2] = f1tl;
    wp.src[3] = fc2W; wp.Hd[3] = f2th; wp.Ld[3] = f2tl;

    // ---- binned edge build (wprep merged into binA as extra blocks) ----
    binA<<<dim3(NT + WXB, 2), 256, 0, stream>>>(ba, wp);
    binB<<<dim3(1, 2, 2), 512, 0, stream>>>(ba);
    binC<<<dim3(NT, 2), 256, 0, stream>>>(ba);

    FinArgs fa = {};
    fa.n = N;
    for (int i = 0; i < 2; ++i) {
        fa.pairs[i] = pairs_[i]; fa.srcS[i] = srcS_[i];
        fa.totD[i] = ba.totD[i]; fa.baseD[i] = ba.baseD[i];
        fa.totS[i] = ba.totS[i]; fa.baseS[i] = ba.baseS[i];
        fa.row_ptr[i] = rp_[i]; fa.row_end[i] = re_[i];
        fa.edge_srt[i] = esrt_[i];
        fa.ns[i] = ns_[i]; fa.nd[i] = nd_[i];
    }
    finalize<<<dim3(NBK, 2), 256, 0, stream>>>(fa);

    // ---- per-graph buffer aliases ----
    float* T[2];
    for (int i = 0; i < 2; ++i)
        T[i] = (float*)R2[i];                          // N*128 fp32 = N*256 shorts

    int mgrid16 = (N + 15) / 16;

    // ---- fused_g12: gather1 + gemm1 + gemm2 -> T ----
    FusedArgs f12 = {};
    f12.B1h = W1th; f12.B1l = W1tl; f12.B2h = W2th; f12.B2l = W2tl;
    f12.b1v = b1; f12.has_b1 = 1; f12.has_b2 = 0;
    f12.has_rs1 = 1; f12.has_rs2 = 1;
    f12.M = N;
    for (int i = 0; i < 2; ++i) {
        f12.Xg[i] = feat[i];
        f12.rp[i] = rp_[i]; f12.re[i] = re_[i]; f12.ep[i] = esrt_[i];
        f12.sns[i] = ns_[i]; f12.ndv[i] = nd_[i];
        f12.rs1[i] = nd_[i]; f12.rs2[i] = ns_[i];
        f12.C[i] = T[i];
    }
    fused_g<128, 256, 1, 16, 1><<<dim3(mgrid16, 2), 256, 0, stream>>>(f12);

    // ---- fused_g34: gather2 + gemm3 + gemm4 -> out ----
    FusedArgs f34 = {};
    f34.B1h = f1th; f34.B1l = f1tl; f34.B2h = f2th; f34.B2l = f2tl;
    f34.b1v = fc1b; f34.has_b1 = 1; f34.b2v = fc2b; f34.has_b2 = 1;
    f34.has_rs1 = 0; f34.has_rs2 = 0;
    f34.gbias = b2;
    f34.M = N;
    for (int i = 0; i < 2; ++i) {
        f34.Xg[i] = T[i];
        f34.rp[i] = rp_[i]; f34.re[i] = re_[i]; f34.ep[i] = esrt_[i];
        f34.sns[i] = ns_[i]; f34.ndv[i] = nd_[i];
        f34.C[i] = out + (size_t)i * N * NDIM;
    }
    fused_g<128, 128, 2, 16, 2><<<dim3(mgrid16, 2), 256, 0, stream>>>(f34);
}

// Round 13
// 550.921 us; speedup vs baseline: 1.1449x; 1.1449x over previous
//
#include <hip/hip_runtime.h>
#include <math.h>

#define NDIM 128   // in_dim = hid = out_dim
#define H2   256   // 2*hid
#define MAXG 2
#define TPE  8192  // edges per bin tile
#define NBKMAX 512 // max buckets (N <= 65536, 128 nodes/bucket)
#define WXB  192   // wprep blocks appended per y-slice of binA

typedef __attribute__((ext_vector_type(8))) short bf16x8;
typedef __attribute__((ext_vector_type(4))) float f32x4;

__device__ __forceinline__ unsigned short f2bf(float f) {
    unsigned int u = __float_as_uint(f);
    u += 0x7fffu + ((u >> 16) & 1u);           // RNE
    return (unsigned short)(u >> 16);
}
__device__ __forceinline__ float bf2f(unsigned short h) {
    return __uint_as_float(((unsigned int)h) << 16);
}
__device__ __forceinline__ void split2(float f, unsigned short& h, unsigned short& l) {
    h = f2bf(f);
    l = f2bf(f - bf2f(h));
}

// ================= binned edge build (no global atomics) =================
struct BinArgs {
    const int* src[MAXG]; const int* dst[MAXG];
    int* histD[MAXG]; int* histS[MAXG];     // [NT][NBK] counts -> global run offsets
    int* totD[MAXG];  int* baseD[MAXG];
    int* totS[MAXG];  int* baseS[MAXG];
    unsigned int* pairs[MAXG];              // dst-binned packed (dl<<16|src)
    unsigned short* srcS[MAXG];             // src-binned bare src ids
    int E[MAXG]; int NBK; int NT; int n;
};

// weight-prep args (merged into binA as extra blocks)
struct WPArgs {
    const float* src[4];
    unsigned short* Hd[4]; unsigned short* Ld[4];
};

__global__ __launch_bounds__(256) void binA(BinArgs a, WPArgs w) {
    int t = blockIdx.x, tid = threadIdx.x;
    if (t >= a.NT) {
        // ---- wprep path: transpose + split all 4 weights ----
        int i = (blockIdx.y * WXB + (t - a.NT)) * 256 + tid;
        const float* Wsrc; unsigned short *Hd, *Ld; int K, Nc, idx;
        if (i < 32768)       { Wsrc = w.src[0]; Hd = w.Hd[0]; Ld = w.Ld[0]; K = 128; Nc = 256; idx = i; }
        else if (i < 65536)  { Wsrc = w.src[1]; Hd = w.Hd[1]; Ld = w.Ld[1]; K = 256; Nc = 128; idx = i - 32768; }
        else if (i < 81920)  { Wsrc = w.src[2]; Hd = w.Hd[2]; Ld = w.Ld[2]; K = 128; Nc = 128; idx = i - 65536; }
        else                 { Wsrc = w.src[3]; Hd = w.Hd[3]; Ld = w.Ld[3]; K = 128; Nc = 128; idx = i - 81920; }
        int k = idx / Nc, n = idx % Nc;
        unsigned short h, l;
        split2(Wsrc[idx], h, l);
        Hd[n * K + k] = h;
        Ld[n * K + k] = l;
        return;
    }
    __shared__ int cntD[NBKMAX], cntS[NBKMAX];
    int g = blockIdx.y;
    for (int b = tid; b < NBKMAX; b += 256) { cntD[b] = 0; cntS[b] = 0; }
    __syncthreads();
    int E = a.E[g];
    int base = t * TPE;
#pragma unroll
    for (int k = 0; k < TPE / 256; ++k) {
        int e = base + k * 256 + tid;
        if (e < E) {
            atomicAdd(&cntD[a.dst[g][e] >> 7], 1);
            atomicAdd(&cntS[a.src[g][e] >> 7], 1);
        }
    }
    __syncthreads();
    for (int b = tid; b < a.NBK; b += 256) {
        a.histD[g][t * a.NBK + b] = cntD[b];
        a.histS[g][t * a.NBK + b] = cntS[b];
    }
}

// fused: per-bucket totals + exclusive scan + rewrite hist to global run offsets
__global__ __launch_bounds__(512) void binB(BinArgs a) {
    int g = blockIdx.y, side = blockIdx.z;
    int* hist = side ? a.histS[g] : a.histD[g];
    int* tot  = side ? a.totS[g]  : a.totD[g];
    int* base = side ? a.baseS[g] : a.baseD[g];
    __shared__ int s[512];
    int b = threadIdx.x;
    int v = 0;
    if (b < a.NBK)
        for (int t = 0; t < a.NT; ++t) v += hist[t * a.NBK + b];
    s[b] = v;
    __syncthreads();
    for (int off = 1; off < 512; off <<= 1) {
        int u = (b >= off) ? s[b - off] : 0;
        __syncthreads();
        s[b] += u;
        __syncthreads();
    }
    int excl = s[b] - v;
    if (b < a.NBK) {
        tot[b] = v;
        base[b] = excl;
        int run = excl;
        for (int t = 0; t < a.NT; ++t) {
            int h = hist[t * a.NBK + b];
            hist[t * a.NBK + b] = run;
            run += h;
        }
    }
}

__global__ __launch_bounds__(256) void binC(BinArgs a) {
    __shared__ int offD[NBKMAX], offS[NBKMAX];
    int g = blockIdx.y, t = blockIdx.x, tid = threadIdx.x;
    for (int b = tid; b < a.NBK; b += 256) {
        offD[b] = a.histD[g][t * a.NBK + b];
        offS[b] = a.histS[g][t * a.NBK + b];
    }
    __syncthreads();
    int E = a.E[g];
    int base = t * TPE;
    unsigned int* pairs = a.pairs[g];
    unsigned short* ss = a.srcS[g];
#pragma unroll
    for (int k = 0; k < TPE / 256; ++k) {
        int e = base + k * 256 + tid;
        if (e < E) {
            int s = a.src[g][e], d = a.dst[g][e];
            int pos = atomicAdd(&offD[d >> 7], 1);
            pairs[pos] = ((unsigned int)(d & 127) << 16) | (unsigned int)s;
            int posS = atomicAdd(&offS[s >> 7], 1);
            ss[posS] = (unsigned short)s;
        }
    }
}

// fused: out-degree hist (-> ns) + per-bucket counting sort (-> CSR, nd, u16 edges)
struct FinArgs {
    const unsigned int* pairs[MAXG];
    const unsigned short* srcS[MAXG];
    const int* totD[MAXG]; const int* baseD[MAXG];
    const int* totS[MAXG]; const int* baseS[MAXG];
    int* row_ptr[MAXG]; int* row_end[MAXG];
    unsigned short* edge_srt[MAXG];
    float* ns[MAXG]; float* nd[MAXG];
    int n;
};

__global__ __launch_bounds__(256) void finalize(FinArgs a) {
    __shared__ int cnt[128], hist[128], scn[128], cur[128];
    int g = blockIdx.y, bkt = blockIdx.x, tid = threadIdx.x;
    if (tid < 128) { cnt[tid] = 0; hist[tid] = 0; }
    __syncthreads();
    // --- out-degree from src-binned segment -> ns ---
    {
        int base = a.baseS[g][bkt], tot = a.totS[g][bkt];
        const unsigned short* ss = a.srcS[g];
        for (int i = tid; i < tot; i += 256)
            atomicAdd(&cnt[ss[base + i] & 127], 1);
    }
    // --- in-degree hist of dst-binned pairs ---
    int cntE = a.totD[g][bkt], base = a.baseD[g][bkt];
    const unsigned int* pp = a.pairs[g] + base;
    for (int i = tid; i < cntE; i += 256)
        atomicAdd(&hist[pp[i] >> 16], 1);
    __syncthreads();
    if (tid < 128) {
        int node = bkt * 128 + tid;
        if (node < a.n) {
            int c = cnt[tid];
            a.ns[g][node] = rsqrtf((float)(c > 1 ? c : 1));
        }
        scn[tid] = hist[tid];
    }
    __syncthreads();
    for (int off = 1; off < 128; off <<= 1) {
        int v = (tid < 128 && tid >= off) ? scn[tid - off] : 0;
        __syncthreads();
        if (tid < 128) scn[tid] += v;
        __syncthreads();
    }
    if (tid < 128) {
        int incl = scn[tid];
        int h = hist[tid];
        cur[tid] = incl - h;
        int node = bkt * 128 + tid;
        if (node < a.n) {
            a.row_ptr[g][node] = base + incl - h;
            a.row_end[g][node] = base + incl;
            a.nd[g][node] = rsqrtf((float)(h > 1 ? h : 1));
        }
    }
    __syncthreads();
    for (int i = tid; i < cntE; i += 256) {
        unsigned int p = pp[i];
        int pos = atomicAdd(&cur[p >> 16], 1);
        a.edge_srt[g][base + pos] = (unsigned short)(p & 0xFFFF);
    }
}

// ====== GATHER + FUSED double-GEMM, one kernel, 512 threads (8 waves) ======
// ROWS=32 — the measured optimum (r11, 551.5 us). r12's 256-thr/ROWS=16 variant
// REGRESSED (83% occupancy but hbm 2.2->1.68 TB/s): the random-gather service
// rate is capped below the CU level; more chains only multiplied per-block
// overheads. This config is the equilibrium of the gather||GEMM structure.
// GMODE 1: acc += X[src]*sns[src]       (gather1 semantics)
// GMODE 2: acc += X[src]; relu(acc*nd + gbias)  (gather2 semantics)
struct FusedArgs {
    const float* Xg[MAXG];                         // gather source (fp32, NDIM cols)
    const int* rp[MAXG]; const int* re[MAXG];
    const unsigned short* ep[MAXG];
    const float* sns[MAXG];                        // GMODE1 per-src scale
    const float* ndv[MAXG];                        // GMODE2 per-row scale
    const float* gbias;                            // GMODE2 bias
    const unsigned short* B1h; const unsigned short* B1l;
    const unsigned short* B2h; const unsigned short* B2l;
    const float* rs1[MAXG]; const float* rs2[MAXG];
    const float* b1v; const float* b2v;
    float* C[MAXG];
    int M, has_rs1, has_rs2, has_b1, has_b2;
};

template <int K1, int N1, int ACT1, int ROWS, int GMODE>
__global__ __launch_bounds__(512, 6) void fused_g(FusedArgs a) {
    constexpr int IR   = ROWS / 16;
    constexpr int SH_A = ROWS * K1;                 // shorts per plane (linear)
    constexpr int SH_X = ROWS * N1;
    constexpr int SH   = (2 * SH_A > 2 * SH_X) ? 2 * SH_A : 2 * SH_X;
    __shared__ __align__(16) unsigned short S[SH];
    unsigned short* As_h = S;
    unsigned short* As_l = S + SH_A;
    unsigned short* Xs_h = S;                       // union: A dead before X written
    unsigned short* Xs_l = S + SH_X;

    int g = blockIdx.y;
    const unsigned short* __restrict__ B1h = a.B1h;
    const unsigned short* __restrict__ B1l = a.B1l;
    const unsigned short* __restrict__ B2h = a.B2h;
    const unsigned short* __restrict__ B2l = a.B2l;

    int tid  = threadIdx.x;
    int wave = tid >> 6, lane = tid & 63;
    int quad = lane >> 4, l16 = lane & 15;
    int rowBase = blockIdx.x * ROWS;
    int M = a.M;

    // ---- phase 0: gather ROWS rows -> As (split h/l, swizzled) ----
    {
        int half  = tid >> 5;                       // 0..15 half-wave id
        int glane = tid & 31;
        const float* X   = a.Xg[g];
        const float* sns = a.sns[g];
        const unsigned short* ep = a.ep[g];
        int base = glane * 4;
#pragma unroll
        for (int ps = 0; ps < ROWS / 16; ++ps) {
            int row  = ps * 16 + half;
            int grow = rowBase + row;
            float4 acc = make_float4(0.f, 0.f, 0.f, 0.f);
            if (grow < M) {
                int j = a.rp[g][grow], end = a.re[g][grow];
                if (GMODE == 1) {
                    // 8-edge groups: 8 loads in flight, then two sequential 4-nests
                    for (; j + 7 < end; j += 8) {
                        int s0 = ep[j], s1 = ep[j + 1], s2 = ep[j + 2], s3 = ep[j + 3];
                        int s4 = ep[j + 4], s5 = ep[j + 5], s6 = ep[j + 6], s7 = ep[j + 7];
                        float n0 = sns[s0], n1 = sns[s1], n2 = sns[s2], n3 = sns[s3];
                        float n4 = sns[s4], n5 = sns[s5], n6 = sns[s6], n7 = sns[s7];
                        float4 v0 = *(const float4*)(X + (size_t)s0 * NDIM + base);
                        float4 v1 = *(const float4*)(X + (size_t)s1 * NDIM + base);
                        float4 v2 = *(const float4*)(X + (size_t)s2 * NDIM + base);
                        float4 v3 = *(const float4*)(X + (size_t)s3 * NDIM + base);
                        float4 v4 = *(const float4*)(X + (size_t)s4 * NDIM + base);
                        float4 v5 = *(const float4*)(X + (size_t)s5 * NDIM + base);
                        float4 v6 = *(const float4*)(X + (size_t)s6 * NDIM + base);
                        float4 v7 = *(const float4*)(X + (size_t)s7 * NDIM + base);
                        __builtin_amdgcn_sched_barrier(0);  // keep all 8 loads above fmas
                        acc.x = fmaf(v0.x, n0, fmaf(v1.x, n1, fmaf(v2.x, n2, fmaf(v3.x, n3, acc.x))));
                        acc.y = fmaf(v0.y, n0, fmaf(v1.y, n1, fmaf(v2.y, n2, fmaf(v3.y, n3, acc.y))));
                        acc.z = fmaf(v0.z, n0, fmaf(v1.z, n1, fmaf(v2.z, n2, fmaf(v3.z, n3, acc.z))));
                        acc.w = fmaf(v0.w, n0, fmaf(v1.w, n1, fmaf(v2.w, n2, fmaf(v3.w, n3, acc.w))));
                        acc.x = fmaf(v4.x, n4, fmaf(v5.x, n5, fmaf(v6.x, n6, fmaf(v7.x, n7, acc.x))));
                        acc.y = fmaf(v4.y, n4, fmaf(v5.y, n5, fmaf(v6.y, n6, fmaf(v7.y, n7, acc.y))));
                        acc.z = fmaf(v4.z, n4, fmaf(v5.z, n5, fmaf(v6.z, n6, fmaf(v7.z, n7, acc.z))));
                        acc.w = fmaf(v4.w, n4, fmaf(v5.w, n5, fmaf(v6.w, n6, fmaf(v7.w, n7, acc.w))));
                    }
                    for (; j + 3 < end; j += 4) {
                        int s0 = ep[j], s1 = ep[j + 1], s2 = ep[j + 2], s3 = ep[j + 3];
                        float n0 = sns[s0], n1 = sns[s1], n2 = sns[s2], n3 = sns[s3];
                        float4 v0 = *(const float4*)(X + (size_t)s0 * NDIM + base);
                        float4 v1 = *(const float4*)(X + (size_t)s1 * NDIM + base);
                        float4 v2 = *(const float4*)(X + (size_t)s2 * NDIM + base);
                        float4 v3 = *(const float4*)(X + (size_t)s3 * NDIM + base);
                        acc.x = fmaf(v0.x, n0, fmaf(v1.x, n1, fmaf(v2.x, n2, fmaf(v3.x, n3, acc.x))));
                        acc.y = fmaf(v0.y, n0, fmaf(v1.y, n1, fmaf(v2.y, n2, fmaf(v3.y, n3, acc.y))));
                        acc.z = fmaf(v0.z, n0, fmaf(v1.z, n1, fmaf(v2.z, n2, fmaf(v3.z, n3, acc.z))));
                        acc.w = fmaf(v0.w, n0, fmaf(v1.w, n1, fmaf(v2.w, n2, fmaf(v3.w, n3, acc.w))));
                    }
                    for (; j < end; ++j) {
                        int s0 = ep[j];
                        float n0 = sns[s0];
                        float4 v0 = *(const float4*)(X + (size_t)s0 * NDIM + base);
                        acc.x = fmaf(v0.x, n0, acc.x); acc.y = fmaf(v0.y, n0, acc.y);
                        acc.z = fmaf(v0.z, n0, acc.z); acc.w = fmaf(v0.w, n0, acc.w);
                    }
                } else {
                    for (; j + 7 < end; j += 8) {
                        int s0 = ep[j], s1 = ep[j + 1], s2 = ep[j + 2], s3 = ep[j + 3];
                        int s4 = ep[j + 4], s5 = ep[j + 5], s6 = ep[j + 6], s7 = ep[j + 7];
                        float4 v0 = *(const float4*)(X + (size_t)s0 * NDIM + base);
                        float4 v1 = *(const float4*)(X + (size_t)s1 * NDIM + base);
                        float4 v2 = *(const float4*)(X + (size_t)s2 * NDIM + base);
                        float4 v3 = *(const float4*)(X + (size_t)s3 * NDIM + base);
                        float4 v4 = *(const float4*)(X + (size_t)s4 * NDIM + base);
                        float4 v5 = *(const float4*)(X + (size_t)s5 * NDIM + base);
                        float4 v6 = *(const float4*)(X + (size_t)s6 * NDIM + base);
                        float4 v7 = *(const float4*)(X + (size_t)s7 * NDIM + base);
                        __builtin_amdgcn_sched_barrier(0);
                        acc.x += v0.x + v1.x + v2.x + v3.x;
                        acc.y += v0.y + v1.y + v2.y + v3.y;
                        acc.z += v0.z + v1.z + v2.z + v3.z;
                        acc.w += v0.w + v1.w + v2.w + v3.w;
                        acc.x += v4.x + v5.x + v6.x + v7.x;
                        acc.y += v4.y + v5.y + v6.y + v7.y;
                        acc.z += v4.z + v5.z + v6.z + v7.z;
                        acc.w += v4.w + v5.w + v6.w + v7.w;
                    }
                    for (; j + 3 < end; j += 4) {
                        int s0 = ep[j], s1 = ep[j + 1], s2 = ep[j + 2], s3 = ep[j + 3];
                        float4 v0 = *(const float4*)(X + (size_t)s0 * NDIM + base);
                        float4 v1 = *(const float4*)(X + (size_t)s1 * NDIM + base);
                        float4 v2 = *(const float4*)(X + (size_t)s2 * NDIM + base);
                        float4 v3 = *(const float4*)(X + (size_t)s3 * NDIM + base);
                        acc.x += v0.x + v1.x + v2.x + v3.x;
                        acc.y += v0.y + v1.y + v2.y + v3.y;
                        acc.z += v0.z + v1.z + v2.z + v3.z;
                        acc.w += v0.w + v1.w + v2.w + v3.w;
                    }
                    for (; j < end; ++j) {
                        int s0 = ep[j];
                        float4 v0 = *(const float4*)(X + (size_t)s0 * NDIM + base);
                        acc.x += v0.x; acc.y += v0.y; acc.z += v0.z; acc.w += v0.w;
                    }
                }
            }
            float v[4] = {acc.x, acc.y, acc.z, acc.w};
            if (GMODE == 2) {
                float s = (grow < M) ? a.ndv[g][grow] : 0.f;
#pragma unroll
                for (int c = 0; c < 4; ++c)
                    v[c] = fmaxf(v[c] * s + a.gbias[base + c], 0.f);
            }
            unsigned short h[4], l[4];
#pragma unroll
            for (int c = 0; c < 4; ++c) split2(v[c], h[c], l[c]);
            // swizzled LDS write: cols glane*4..+3 all in chunk oc=glane>>1
            int oc = glane >> 1, within = (glane & 1) * 4;
            int sc = oc ^ (row & 7);
            *(ushort4*)(As_h + row * K1 + sc * 8 + within) = make_ushort4(h[0], h[1], h[2], h[3]);
            *(ushort4*)(As_l + row * K1 + sc * 8 + within) = make_ushort4(l[0], l[1], l[2], l[3]);
        }
    }

    constexpr int J1  = (N1 / 128 > 0) ? N1 / 128 : 1;  // pass1 16-col groups per wave
    constexpr int KT1 = K1 / 32;
    constexpr int KT2 = N1 / 32;
    int wcol1 = wave * (N1 / 8);
    int wcol2 = wave * 16;

    size_t b1off[J1];
#pragma unroll
    for (int j = 0; j < J1; ++j)
        b1off[j] = (size_t)(wcol1 + j * 16 + l16) * K1 + quad * 8;
    size_t b2off = (size_t)(wcol2 + l16) * N1 + quad * 8;

    auto loadB1 = [&](int kt, bf16x8 (&bh)[J1], bf16x8 (&bl)[J1]) {
#pragma unroll
        for (int j = 0; j < J1; ++j) {
            bh[j] = *(const bf16x8*)(B1h + b1off[j] + kt * 32);
            bl[j] = *(const bf16x8*)(B1l + b1off[j] + kt * 32);
        }
    };
    auto loadB2 = [&](int kt, bf16x8 (&bh)[1], bf16x8 (&bl)[1]) {
        bh[0] = *(const bf16x8*)(B2h + b2off + kt * 32);
        bl[0] = *(const bf16x8*)(B2l + b2off + kt * 32);
    };

    // ---- preload B1(kt=0): latency hides under barrier ----
    bf16x8 b1hA[J1], b1lA[J1], b1hB[J1], b1lB[J1];
    loadB1(0, b1hA, b1lA);
    __syncthreads();

    // ---- pass 1: ROWS x N1, ping-pong B1 buffers ----
    f32x4 acc1[IR][J1] = {};
    auto stepP1 = [&](int kt, bf16x8 (&bh)[J1], bf16x8 (&bl)[J1]) {
        bf16x8 af[IR], alf[IR];
#pragma unroll
        for (int i = 0; i < IR; ++i) {
            int r  = i * 16 + l16;
            int sc = (kt * 4 + quad) ^ (r & 7);    // swizzled read
            af[i]  = *(const bf16x8*)(As_h + r * K1 + sc * 8);
            alf[i] = *(const bf16x8*)(As_l + r * K1 + sc * 8);
        }
#pragma unroll
        for (int i = 0; i < IR; ++i)
#pragma unroll
            for (int j = 0; j < J1; ++j) {
                acc1[i][j] = __builtin_amdgcn_mfma_f32_16x16x32_bf16(af[i],  bh[j], acc1[i][j], 0, 0, 0);
                acc1[i][j] = __builtin_amdgcn_mfma_f32_16x16x32_bf16(alf[i], bh[j], acc1[i][j], 0, 0, 0);
                acc1[i][j] = __builtin_amdgcn_mfma_f32_16x16x32_bf16(af[i],  bl[j], acc1[i][j], 0, 0, 0);
            }
    };
#pragma unroll
    for (int kt = 0; kt < KT1; kt += 2) {
        if (kt + 1 < KT1) loadB1(kt + 1, b1hB, b1lB);
        stepP1(kt, b1hA, b1lA);
        if (kt + 2 < KT1) loadB1(kt + 2, b1hA, b1lA);
        if (kt + 1 < KT1) stepP1(kt + 1, b1hB, b1lB);
    }

    // ---- preload B2(kt=0): latency hides under epilogue1 + barriers ----
    bf16x8 b2hA[1], b2lA[1], b2hB[1], b2lB[1];
    loadB2(0, b2hA, b2lA);

    __syncthreads();   // all waves done reading As before Xs overwrite

    // ---- epilogue 1: act -> split -> swizzled LDS hidden tile ----
    const float* rs1p = a.has_rs1 ? a.rs1[g] : nullptr;
#pragma unroll
    for (int i = 0; i < IR; ++i) {
#pragma unroll
        for (int rr = 0; rr < 4; ++rr) {
            int row  = i * 16 + quad * 4 + rr;
            int grow = rowBase + row;
            float rs = 1.0f;
            if (rs1p) rs = (grow < M) ? rs1p[grow] : 0.0f;
#pragma unroll
            for (int j = 0; j < J1; ++j) {
                int col = wcol1 + j * 16 + l16;
                float v = acc1[i][j][rr] * rs;
                if (a.has_b1) v += a.b1v[col];
                if (ACT1 == 1) v = fmaxf(v, 0.f);
                else           v = v > 0.f ? v : expm1f(v);
                unsigned short h, l;
                split2(v, h, l);
                int oc = col >> 3, within = col & 7;
                int sc = oc ^ (row & 7);
                Xs_h[row * N1 + sc * 8 + within] = h;
                Xs_l[row * N1 + sc * 8 + within] = l;
            }
        }
    }
    __syncthreads();

    // ---- pass 2: hidden(ROWS x N1) @ B2(N1 x 128), ping-pong B2 buffers ----
    f32x4 acc2[IR][1] = {};
    auto stepP2 = [&](int kt, bf16x8 (&bh)[1], bf16x8 (&bl)[1]) {
        bf16x8 xf[IR], xlf[IR];
#pragma unroll
        for (int i = 0; i < IR; ++i) {
            int r  = i * 16 + l16;
            int sc = (kt * 4 + quad) ^ (r & 7);
            xf[i]  = *(const bf16x8*)(Xs_h + r * N1 + sc * 8);
            xlf[i] = *(const bf16x8*)(Xs_l + r * N1 + sc * 8);
        }
#pragma unroll
        for (int i = 0; i < IR; ++i) {
            acc2[i][0] = __builtin_amdgcn_mfma_f32_16x16x32_bf16(xf[i],  bh[0], acc2[i][0], 0, 0, 0);
            acc2[i][0] = __builtin_amdgcn_mfma_f32_16x16x32_bf16(xlf[i], bh[0], acc2[i][0], 0, 0, 0);
            acc2[i][0] = __builtin_amdgcn_mfma_f32_16x16x32_bf16(xf[i],  bl[0], acc2[i][0], 0, 0, 0);
        }
    };
#pragma unroll
    for (int kt = 0; kt < KT2; kt += 2) {
        if (kt + 1 < KT2) loadB2(kt + 1, b2hB, b2lB);
        stepP2(kt, b2hA, b2lA);
        if (kt + 2 < KT2) loadB2(kt + 2, b2hA, b2lA);
        if (kt + 1 < KT2) stepP2(kt + 1, b2hB, b2lB);
    }

    // ---- epilogue 2: fp32 out ----
    const float* rs2p = a.has_rs2 ? a.rs2[g] : nullptr;
#pragma unroll
    for (int i = 0; i < IR; ++i) {
#pragma unroll
        for (int rr = 0; rr < 4; ++rr) {
            int grow = rowBase + i * 16 + quad * 4 + rr;
            if (grow >= M) continue;
            float rs = rs2p ? rs2p[grow] : 1.0f;
            int col = wcol2 + l16;
            float v = acc2[i][0][rr] * rs;
            if (a.has_b2) v += a.b2v[col];
            a.C[g][(size_t)grow * NDIM + col] = v;
        }
    }
}

extern "C" void kernel_launch(void* const* d_in, const int* in_sizes, int n_in,
                              void* d_out, int out_size, void* d_ws, size_t ws_size,
                              hipStream_t stream) {
    const float* feat[2] = {(const float*)d_in[0], (const float*)d_in[1]};
    const int*   ei[2]   = {(const int*)d_in[2], (const int*)d_in[3]};
    const float* W1   = (const float*)d_in[4];
    const float* b1   = (const float*)d_in[5];
    const float* W2   = (const float*)d_in[6];
    const float* b2   = (const float*)d_in[7];
    const float* fc1W = (const float*)d_in[8];
    const float* fc1b = (const float*)d_in[9];
    const float* fc2W = (const float*)d_in[10];
    const float* fc2b = (const float*)d_in[11];
    int N = in_sizes[0] / NDIM;     // 50000 (< 65536: u16 node-id packing valid)
    float* out = (float*)d_out;

    int Emax = 0;
    for (int g = 0; g < 2; ++g) { int E = in_sizes[2 + g] / 2; if (E > Emax) Emax = E; }
    int NBK = (N + 127) / 128;
    int NT  = (Emax + TPE - 1) / TPE;

    // ---- workspace layout ----
    char* p = (char*)d_ws;
    float* ns_[2]; float* nd_[2];
    for (int i = 0; i < 2; ++i) { ns_[i] = (float*)p; p += (size_t)N * 4; }
    for (int i = 0; i < 2; ++i) { nd_[i] = (float*)p; p += (size_t)N * 4; }
    int* rp_[2]; int* re_[2]; unsigned short* esrt_[2];
    for (int i = 0; i < 2; ++i) { rp_[i] = (int*)p; p += (size_t)N * 4; }
    for (int i = 0; i < 2; ++i) { re_[i] = (int*)p; p += (size_t)N * 4; }
    for (int i = 0; i < 2; ++i) { esrt_[i] = (unsigned short*)p; p += (size_t)Emax * 2; }
    unsigned short* R1[2]; unsigned short* R2[2];
    for (int i = 0; i < 2; ++i) { R1[i] = (unsigned short*)p; p += (size_t)N * NDIM * 2 * 2; }
    for (int i = 0; i < 2; ++i) { R2[i] = (unsigned short*)p; p += (size_t)N * H2 * 2 * 2; }
    unsigned short* W1th = (unsigned short*)p; p += (size_t)NDIM * H2 * 2;
    unsigned short* W1tl = (unsigned short*)p; p += (size_t)NDIM * H2 * 2;
    unsigned short* W2th = (unsigned short*)p; p += (size_t)H2 * NDIM * 2;
    unsigned short* W2tl = (unsigned short*)p; p += (size_t)H2 * NDIM * 2;
    unsigned short* f1th = (unsigned short*)p; p += (size_t)NDIM * NDIM * 2;
    unsigned short* f1tl = (unsigned short*)p; p += (size_t)NDIM * NDIM * 2;
    unsigned short* f2th = (unsigned short*)p; p += (size_t)NDIM * NDIM * 2;
    unsigned short* f2tl = (unsigned short*)p; p += (size_t)NDIM * NDIM * 2;
    int* tb = (int*)p; p += (size_t)2 * 4 * NBK * 4;   // totD/baseD/totS/baseS per graph

    // aliases with disjoint lifetimes:
    //  - histD/histS at R2[i]+0 (dead after binC); pairs at R2[i]+1MB (dead after finalize)
    //  - srcS at R1[i] (dead after finalize)
    //  - T (fp32, N*128) at R2[i][0 : N*256 shorts] (written by fused_g12 after
    //    pairs dead; read by fused_g34)
    int* histD_[2]; int* histS_[2]; unsigned int* pairs_[2]; unsigned short* srcS_[2];
    for (int i = 0; i < 2; ++i) {
        histD_[i] = (int*)R2[i];
        histS_[i] = (int*)R2[i] + (size_t)NT * NBK;
        pairs_[i] = (unsigned int*)((char*)R2[i] + (1 << 20));  // 1MB offset > hist tables
        srcS_[i]  = (unsigned short*)R1[i];
    }

    BinArgs ba = {};
    ba.NBK = NBK; ba.NT = NT; ba.n = N;
    for (int i = 0; i < 2; ++i) {
        int E = in_sizes[2 + i] / 2;
        ba.src[i] = ei[i]; ba.dst[i] = ei[i] + E; ba.E[i] = E;
        ba.histD[i] = histD_[i]; ba.histS[i] = histS_[i];
        ba.totD[i]  = tb + (size_t)i * 4 * NBK;
        ba.baseD[i] = tb + (size_t)i * 4 * NBK + NBK;
        ba.totS[i]  = tb + (size_t)i * 4 * NBK + 2 * NBK;
        ba.baseS[i] = tb + (size_t)i * 4 * NBK + 3 * NBK;
        ba.pairs[i] = pairs_[i]; ba.srcS[i] = srcS_[i];
    }

    WPArgs wp = {};
    wp.src[0] = W1;   wp.Hd[0] = W1th; wp.Ld[0] = W1tl;
    wp.src[1] = W2;   wp.Hd[1] = W2th; wp.Ld[1] = W2tl;
    wp.src[2] = fc1W; wp.Hd[2] = f1th; wp.Ld[2] = f1tl;
    wp.src[3] = fc2W; wp.Hd[3] = f2th; wp.Ld[3] = f2tl;

    // ---- binned edge build (wprep merged into binA as extra blocks) ----
    binA<<<dim3(NT + WXB, 2), 256, 0, stream>>>(ba, wp);
    binB<<<dim3(1, 2, 2), 512, 0, stream>>>(ba);
    binC<<<dim3(NT, 2), 256, 0, stream>>>(ba);

    FinArgs fa = {};
    fa.n = N;
    for (int i = 0; i < 2; ++i) {
        fa.pairs[i] = pairs_[i]; fa.srcS[i] = srcS_[i];
        fa.totD[i] = ba.totD[i]; fa.baseD[i] = ba.baseD[i];
        fa.totS[i] = ba.totS[i]; fa.baseS[i] = ba.baseS[i];
        fa.row_ptr[i] = rp_[i]; fa.row_end[i] = re_[i];
        fa.edge_srt[i] = esrt_[i];
        fa.ns[i] = ns_[i]; fa.nd[i] = nd_[i];
    }
    finalize<<<dim3(NBK, 2), 256, 0, stream>>>(fa);

    // ---- per-graph buffer aliases ----
    float* T[2];
    for (int i = 0; i < 2; ++i)
        T[i] = (float*)R2[i];                          // N*128 fp32 = N*256 shorts

    int mgrid32 = (N + 31) / 32;

    // ---- fused_g12: gather1 + gemm1 + gemm2 -> T ----
    FusedArgs f12 = {};
    f12.B1h = W1th; f12.B1l = W1tl; f12.B2h = W2th; f12.B2l = W2tl;
    f12.b1v = b1; f12.has_b1 = 1; f12.has_b2 = 0;
    f12.has_rs1 = 1; f12.has_rs2 = 1;
    f12.M = N;
    for (int i = 0; i < 2; ++i) {
        f12.Xg[i] = feat[i];
        f12.rp[i] = rp_[i]; f12.re[i] = re_[i]; f12.ep[i] = esrt_[i];
        f12.sns[i] = ns_[i]; f12.ndv[i] = nd_[i];
        f12.rs1[i] = nd_[i]; f12.rs2[i] = ns_[i];
        f12.C[i] = T[i];
    }
    fused_g<128, 256, 1, 32, 1><<<dim3(mgrid32, 2), 512, 0, stream>>>(f12);

    // ---- fused_g34: gather2 + gemm3 + gemm4 -> out ----
    FusedArgs f34 = {};
    f34.B1h = f1th; f34.B1l = f1tl; f34.B2h = f2th; f34.B2l = f2tl;
    f34.b1v = fc1b; f34.has_b1 = 1; f34.b2v = fc2b; f34.has_b2 = 1;
    f34.has_rs1 = 0; f34.has_rs2 = 0;
    f34.gbias = b2;
    f34.M = N;
    for (int i = 0; i < 2; ++i) {
        f34.Xg[i] = T[i];
        f34.rp[i] = rp_[i]; f34.re[i] = re_[i]; f34.ep[i] = esrt_[i];
        f34.sns[i] = ns_[i]; f34.ndv[i] = nd_[i];
        f34.C[i] = out + (size_t)i * N * NDIM;
    }
    fused_g<128, 128, 2, 32, 2><<<dim3(mgrid32, 2), 512, 0, stream>>>(f34);
}